// Round 4
// baseline (85.430 us; speedup 1.0000x reference)
//
#include <hip/hip_runtime.h>

// out[b,t,c] = x[b,t,c] + sum_{s=max(t-8,0)}^{t-1} isi[b,s,c]
// isi[..., f]    = h[f]*x[f]   - h[f+64]*x[f+64]   (f < 64)
// isi[..., f+64] = h[f]*x[f+64] + h[f+64]*x[f]
//
// B=32, T=8192, C=128, W=8.
// float4 version: each lane owns 4 adjacent channel pairs (4c..4c+3, +64),
// c = lane&15. A 16-lane group covers one (b, chunk) column; a wave processes
// 4 adjacent chunks. TC=16 timesteps per chunk -> 16384 columns -> 4096 waves
// (16 waves/CU). Register ring of last 8 isi values + running window sums,
// inner loop unrolled by 8 (compile-time ring indices). 16 B/lane loads for
// max bytes-in-flight; nontemporal stores for the streamed output.

typedef float f4 __attribute__((ext_vector_type(4)));

constexpr int TLEN   = 8192;
constexpr int CCH    = 128;
constexpr int FHALF  = 64;
constexpr int WWIN   = 8;
constexpr int TC     = 16;            // timesteps per column-chunk
constexpr int NCHUNK = TLEN / TC;     // 512
constexpr int NB     = 32;

__global__ __launch_bounds__(256, 4) void isi_window_kernel(
    const float* __restrict__ x, const float* __restrict__ h,
    float* __restrict__ out)
{
    const int wave = threadIdx.x >> 6;
    const int lane = threadIdx.x & 63;
    const int c4   = (lane & 15) * 4;                 // first of 4 adjacent channels
    const int sub  = lane >> 4;                       // which column within the wave

    const int gw    = blockIdx.x * 4 + wave;          // 0 .. 4095
    const int col   = gw * 4 + sub;                   // 0 .. 16383 (= b*NCHUNK + chunk)
    const int b     = col >> 9;                       // col / NCHUNK
    const int chunk = col & (NCHUNK - 1);
    const int t0    = chunk * TC;

    const size_t base = (size_t)b * TLEN * CCH + c4;
    const float* xb = x + base;
    const float* hb = h + base;
    float*       ob = out + base;

    f4 histr[WWIN], histi[WWIN];
    f4 winr = (f4)(0.f), wini = (f4)(0.f);
#pragma unroll
    for (int j = 0; j < WWIN; ++j) {
        histr[j] = (f4)(0.f);
        histi[j] = (f4)(0.f);
    }

    // Warm-up: the 8 timesteps before t0 (chunk 0 starts with an empty window).
    if (t0 > 0) {
        const int tw = t0 - WWIN;
#pragma unroll
        for (int j = 0; j < WWIN; ++j) {
            const size_t off = (size_t)(tw + j) * CCH;
            const f4 xr = *(const f4*)(xb + off);
            const f4 xi = *(const f4*)(xb + off + FHALF);
            const f4 hr = *(const f4*)(hb + off);
            const f4 hi = *(const f4*)(hb + off + FHALF);
            const f4 ir = hr * xr - hi * xi;
            const f4 ii = hr * xi + hi * xr;
            histr[j] = ir; histi[j] = ii;
            winr += ir; wini += ii;
        }
    }

    // Main loop: emit with current window, then slide by one.
    for (int tb = t0; tb < t0 + TC; tb += WWIN) {
#pragma unroll
        for (int j = 0; j < WWIN; ++j) {
            const size_t off = (size_t)(tb + j) * CCH;
            const f4 xr = *(const f4*)(xb + off);
            const f4 xi = *(const f4*)(xb + off + FHALF);
            const f4 hr = *(const f4*)(hb + off);
            const f4 hi = *(const f4*)(hb + off + FHALF);

            const f4 o0 = xr + winr;
            const f4 o1 = xi + wini;
            __builtin_nontemporal_store(o0, (f4*)(ob + off));
            __builtin_nontemporal_store(o1, (f4*)(ob + off + FHALF));

            const f4 ir = hr * xr - hi * xi;
            const f4 ii = hr * xi + hi * xr;

            winr += ir - histr[j];
            wini += ii - histi[j];
            histr[j] = ir; histi[j] = ii;
        }
    }
}

extern "C" void kernel_launch(void* const* d_in, const int* in_sizes, int n_in,
                              void* d_out, int out_size, void* d_ws, size_t ws_size,
                              hipStream_t stream) {
    const float* x = (const float*)d_in[0];
    const float* h = (const float*)d_in[1];
    float* out = (float*)d_out;

    const int total_cols  = NB * NCHUNK;              // 16384 columns
    const int total_waves = total_cols / 4;           // 4096 (4 columns per wave)
    const int blocks      = total_waves / 4;          // 1024 blocks of 4 waves
    isi_window_kernel<<<blocks, 256, 0, stream>>>(x, h, out);
}

// Round 5
// 71.875 us; speedup vs baseline: 1.1886x; 1.1886x over previous
//
#include <hip/hip_runtime.h>

// out[b,t,c] = x[b,t,c] + sum_{s=max(t-8,0)}^{t-1} isi[b,s,c]
// isi[..., f]    = h[f]*x[f]   - h[f+64]*x[f+64]   (f < 64)
// isi[..., f+64] = h[f]*x[f+64] + h[f+64]*x[f]
//
// B=32, T=8192, C=128, W=8.
// float4, TC=32: each lane owns 4 adjacent channel pairs (4c..4c+3, +64),
// c = lane&15. A 16-lane group covers one (b, chunk) column; a wave processes
// 4 adjacent chunks. 8192 columns -> 2048 waves (8 waves/CU). Same 25% warmup
// ratio / HBM traffic as the 70.5us float2/TC=32 config, but 2x bytes in
// flight per load instruction. Register ring of last 8 isi values + running
// window sums, unroll-8 inner loop (compile-time ring indices -> VGPRs).
// Nontemporal stores for the streamed output.

typedef float f4 __attribute__((ext_vector_type(4)));

constexpr int TLEN   = 8192;
constexpr int CCH    = 128;
constexpr int FHALF  = 64;
constexpr int WWIN   = 8;
constexpr int TC     = 32;            // timesteps per column-chunk
constexpr int NCHUNK = TLEN / TC;     // 256
constexpr int NB     = 32;

__global__ __launch_bounds__(256) void isi_window_kernel(
    const float* __restrict__ x, const float* __restrict__ h,
    float* __restrict__ out)
{
    const int wave = threadIdx.x >> 6;
    const int lane = threadIdx.x & 63;
    const int c4   = (lane & 15) * 4;                 // first of 4 adjacent channels
    const int sub  = lane >> 4;                       // which column within the wave

    const int gw    = blockIdx.x * 4 + wave;          // 0 .. 2047
    const int col   = gw * 4 + sub;                   // 0 .. 8191 (= b*NCHUNK + chunk)
    const int b     = col >> 8;                       // col / NCHUNK
    const int chunk = col & (NCHUNK - 1);
    const int t0    = chunk * TC;

    const size_t base = (size_t)b * TLEN * CCH + c4;
    const float* xb = x + base;
    const float* hb = h + base;
    float*       ob = out + base;

    f4 histr[WWIN], histi[WWIN];
    f4 winr = (f4)(0.f), wini = (f4)(0.f);
#pragma unroll
    for (int j = 0; j < WWIN; ++j) {
        histr[j] = (f4)(0.f);
        histi[j] = (f4)(0.f);
    }

    // Warm-up: the 8 timesteps before t0 (chunk 0 starts with an empty window).
    if (t0 > 0) {
        const int tw = t0 - WWIN;
#pragma unroll
        for (int j = 0; j < WWIN; ++j) {
            const size_t off = (size_t)(tw + j) * CCH;
            const f4 xr = *(const f4*)(xb + off);
            const f4 xi = *(const f4*)(xb + off + FHALF);
            const f4 hr = *(const f4*)(hb + off);
            const f4 hi = *(const f4*)(hb + off + FHALF);
            const f4 ir = hr * xr - hi * xi;
            const f4 ii = hr * xi + hi * xr;
            histr[j] = ir; histi[j] = ii;
            winr += ir; wini += ii;
        }
    }

    // Main loop: emit with current window, then slide by one.
    for (int tb = t0; tb < t0 + TC; tb += WWIN) {
#pragma unroll
        for (int j = 0; j < WWIN; ++j) {
            const size_t off = (size_t)(tb + j) * CCH;
            const f4 xr = *(const f4*)(xb + off);
            const f4 xi = *(const f4*)(xb + off + FHALF);
            const f4 hr = *(const f4*)(hb + off);
            const f4 hi = *(const f4*)(hb + off + FHALF);

            const f4 o0 = xr + winr;
            const f4 o1 = xi + wini;
            __builtin_nontemporal_store(o0, (f4*)(ob + off));
            __builtin_nontemporal_store(o1, (f4*)(ob + off + FHALF));

            const f4 ir = hr * xr - hi * xi;
            const f4 ii = hr * xi + hi * xr;

            winr += ir - histr[j];
            wini += ii - histi[j];
            histr[j] = ir; histi[j] = ii;
        }
    }
}

extern "C" void kernel_launch(void* const* d_in, const int* in_sizes, int n_in,
                              void* d_out, int out_size, void* d_ws, size_t ws_size,
                              hipStream_t stream) {
    const float* x = (const float*)d_in[0];
    const float* h = (const float*)d_in[1];
    float* out = (float*)d_out;

    const int total_cols  = NB * NCHUNK;              // 8192 columns
    const int total_waves = total_cols / 4;           // 2048 (4 columns per wave)
    const int blocks      = total_waves / 4;          // 512 blocks of 4 waves
    isi_window_kernel<<<blocks, 256, 0, stream>>>(x, h, out);
}

// Round 6
// 66.142 us; speedup vs baseline: 1.2916x; 1.0867x over previous
//
#include <hip/hip_runtime.h>

// out[b,t,c] = x[b,t,c] + sum_{s=max(t-8,0)}^{t-1} isi[b,s,c]
// isi[..., f]    = h[f]*x[f]   - h[f+64]*x[f+64]   (f < 64)
// isi[..., f+64] = h[f]*x[f+64] + h[f+64]*x[f]
//
// B=32, T=8192, C=128, W=8.
// float2, TC=64: lane owns 2 adjacent channel pairs; half-wave (32 lanes)
// covers one (b, chunk) column; wave processes 2 adjacent chunks. 4096
// columns -> 2048 waves (8/CU, validated by R5). TC=64 cuts warm-up
// redundancy to 12.5% -> demand 416 MB (vs 448 at TC=32); at the ~6.35 TB/s
// demand ceiling that's ~65.5 us. Register ring of last 8 isi values +
// running window sums, unroll-8 (compile-time ring indices -> VGPRs).
// Nontemporal stores keep the write stream from evicting x/h L3 residency.

typedef float f2 __attribute__((ext_vector_type(2)));

constexpr int TLEN   = 8192;
constexpr int CCH    = 128;
constexpr int FHALF  = 64;
constexpr int WWIN   = 8;
constexpr int TC     = 64;            // timesteps per column-chunk
constexpr int NCHUNK = TLEN / TC;     // 128
constexpr int NB     = 32;

__global__ __launch_bounds__(256) void isi_window_kernel(
    const float* __restrict__ x, const float* __restrict__ h,
    float* __restrict__ out)
{
    const int wave = threadIdx.x >> 6;
    const int lane = threadIdx.x & 63;
    const int c2   = (lane & 31) * 2;                 // first channel of the pair-of-pairs
    const int half = lane >> 5;

    const int gw    = blockIdx.x * 4 + wave;          // 0 .. 2047
    const int col   = gw * 2 + half;                  // 0 .. 4095 (= b*NCHUNK + chunk)
    const int b     = col >> 7;                       // col / NCHUNK
    const int chunk = col & (NCHUNK - 1);
    const int t0    = chunk * TC;

    const size_t base = (size_t)b * TLEN * CCH + c2;
    const float* xb = x + base;
    const float* hb = h + base;
    float*       ob = out + base;

    f2 histr[WWIN], histi[WWIN];
    f2 winr = (f2)(0.f), wini = (f2)(0.f);
#pragma unroll
    for (int j = 0; j < WWIN; ++j) {
        histr[j] = (f2)(0.f);
        histi[j] = (f2)(0.f);
    }

    // Warm-up: the 8 timesteps before t0 (chunk 0 starts with an empty window).
    if (t0 > 0) {
        const int tw = t0 - WWIN;
#pragma unroll
        for (int j = 0; j < WWIN; ++j) {
            const size_t off = (size_t)(tw + j) * CCH;
            const f2 xr = *(const f2*)(xb + off);
            const f2 xi = *(const f2*)(xb + off + FHALF);
            const f2 hr = *(const f2*)(hb + off);
            const f2 hi = *(const f2*)(hb + off + FHALF);
            const f2 ir = hr * xr - hi * xi;
            const f2 ii = hr * xi + hi * xr;
            histr[j] = ir; histi[j] = ii;
            winr += ir; wini += ii;
        }
    }

    // Main loop: emit with current window, then slide by one.
    for (int tb = t0; tb < t0 + TC; tb += WWIN) {
#pragma unroll
        for (int j = 0; j < WWIN; ++j) {
            const size_t off = (size_t)(tb + j) * CCH;
            const f2 xr = *(const f2*)(xb + off);
            const f2 xi = *(const f2*)(xb + off + FHALF);
            const f2 hr = *(const f2*)(hb + off);
            const f2 hi = *(const f2*)(hb + off + FHALF);

            const f2 o0 = xr + winr;
            const f2 o1 = xi + wini;
            __builtin_nontemporal_store(o0, (f2*)(ob + off));
            __builtin_nontemporal_store(o1, (f2*)(ob + off + FHALF));

            const f2 ir = hr * xr - hi * xi;
            const f2 ii = hr * xi + hi * xr;

            winr += ir - histr[j];
            wini += ii - histi[j];
            histr[j] = ir; histi[j] = ii;
        }
    }
}

extern "C" void kernel_launch(void* const* d_in, const int* in_sizes, int n_in,
                              void* d_out, int out_size, void* d_ws, size_t ws_size,
                              hipStream_t stream) {
    const float* x = (const float*)d_in[0];
    const float* h = (const float*)d_in[1];
    float* out = (float*)d_out;

    const int total_cols  = NB * NCHUNK;              // 4096 columns
    const int total_waves = total_cols / 2;           // 2048 (2 columns per wave)
    const int blocks      = total_waves / 4;          // 512 blocks of 4 waves
    isi_window_kernel<<<blocks, 256, 0, stream>>>(x, h, out);
}

// Round 7
// 63.453 us; speedup vs baseline: 1.3463x; 1.0424x over previous
//
#include <hip/hip_runtime.h>

// out[b,t,c] = x[b,t,c] + sum_{s=max(t-8,0)}^{t-1} isi[b,s,c]
// isi[..., f]    = h[f]*x[f]   - h[f+64]*x[f+64]   (f < 64)
// isi[..., f+64] = h[f]*x[f+64] + h[f+64]*x[f]
//
// B=32, T=8192, C=128, W=8.
// float2, TC=128: lane owns 2 adjacent channel pairs; half-wave (32 lanes)
// covers one (b, chunk) column; wave processes 2 adjacent chunks. 2048
// columns -> 1024 waves (4/CU). TC=128 cuts warm-up redundancy to 6.25% ->
// demand 400 MB; at the ~6.3 TB/s demand ceiling that's ~63.5 us. All rounds
// R3/R5/R6 sat exactly at the demand ceiling, so bytes are the only lever.
// Register ring of last 8 isi values + running window sums, unroll-8
// (compile-time ring indices -> VGPRs). Nontemporal stores keep the write
// stream from evicting x/h L3 residency.

typedef float f2 __attribute__((ext_vector_type(2)));

constexpr int TLEN   = 8192;
constexpr int CCH    = 128;
constexpr int FHALF  = 64;
constexpr int WWIN   = 8;
constexpr int TC     = 128;           // timesteps per column-chunk
constexpr int NCHUNK = TLEN / TC;     // 64
constexpr int NB     = 32;

__global__ __launch_bounds__(256) void isi_window_kernel(
    const float* __restrict__ x, const float* __restrict__ h,
    float* __restrict__ out)
{
    const int wave = threadIdx.x >> 6;
    const int lane = threadIdx.x & 63;
    const int c2   = (lane & 31) * 2;                 // first channel of the pair-of-pairs
    const int half = lane >> 5;

    const int gw    = blockIdx.x * 4 + wave;          // 0 .. 1023
    const int col   = gw * 2 + half;                  // 0 .. 2047 (= b*NCHUNK + chunk)
    const int b     = col >> 6;                       // col / NCHUNK
    const int chunk = col & (NCHUNK - 1);
    const int t0    = chunk * TC;

    const size_t base = (size_t)b * TLEN * CCH + c2;
    const float* xb = x + base;
    const float* hb = h + base;
    float*       ob = out + base;

    f2 histr[WWIN], histi[WWIN];
    f2 winr = (f2)(0.f), wini = (f2)(0.f);
#pragma unroll
    for (int j = 0; j < WWIN; ++j) {
        histr[j] = (f2)(0.f);
        histi[j] = (f2)(0.f);
    }

    // Warm-up: the 8 timesteps before t0 (chunk 0 starts with an empty window).
    if (t0 > 0) {
        const int tw = t0 - WWIN;
#pragma unroll
        for (int j = 0; j < WWIN; ++j) {
            const size_t off = (size_t)(tw + j) * CCH;
            const f2 xr = *(const f2*)(xb + off);
            const f2 xi = *(const f2*)(xb + off + FHALF);
            const f2 hr = *(const f2*)(hb + off);
            const f2 hi = *(const f2*)(hb + off + FHALF);
            const f2 ir = hr * xr - hi * xi;
            const f2 ii = hr * xi + hi * xr;
            histr[j] = ir; histi[j] = ii;
            winr += ir; wini += ii;
        }
    }

    // Main loop: emit with current window, then slide by one.
    for (int tb = t0; tb < t0 + TC; tb += WWIN) {
#pragma unroll
        for (int j = 0; j < WWIN; ++j) {
            const size_t off = (size_t)(tb + j) * CCH;
            const f2 xr = *(const f2*)(xb + off);
            const f2 xi = *(const f2*)(xb + off + FHALF);
            const f2 hr = *(const f2*)(hb + off);
            const f2 hi = *(const f2*)(hb + off + FHALF);

            const f2 o0 = xr + winr;
            const f2 o1 = xi + wini;
            __builtin_nontemporal_store(o0, (f2*)(ob + off));
            __builtin_nontemporal_store(o1, (f2*)(ob + off + FHALF));

            const f2 ir = hr * xr - hi * xi;
            const f2 ii = hr * xi + hi * xr;

            winr += ir - histr[j];
            wini += ii - histi[j];
            histr[j] = ir; histi[j] = ii;
        }
    }
}

extern "C" void kernel_launch(void* const* d_in, const int* in_sizes, int n_in,
                              void* d_out, int out_size, void* d_ws, size_t ws_size,
                              hipStream_t stream) {
    const float* x = (const float*)d_in[0];
    const float* h = (const float*)d_in[1];
    float* out = (float*)d_out;

    const int total_cols  = NB * NCHUNK;              // 2048 columns
    const int total_waves = total_cols / 2;           // 1024 (2 columns per wave)
    const int blocks      = total_waves / 4;          // 256 blocks of 4 waves
    isi_window_kernel<<<blocks, 256, 0, stream>>>(x, h, out);
}